// Round 4
// baseline (539.246 us; speedup 1.0000x reference)
//
#include <hip/hip_runtime.h>

typedef unsigned short u16;
typedef __attribute__((ext_vector_type(8))) short short8;
typedef __attribute__((ext_vector_type(4))) float floatx4;

#define MFMA16(a, b, c) __builtin_amdgcn_mfma_f32_16x16x32_bf16(a, b, c, 0, 0, 0)

__device__ __forceinline__ float bf2f(u16 u) {
  return __uint_as_float(((unsigned int)u) << 16);
}
__device__ __forceinline__ u16 f2bf(float f) {
  unsigned int u = __float_as_uint(f);
  unsigned int r = (u + 0x7fffu + ((u >> 16) & 1u)) >> 16;
  return (u16)r;
}

// ---------------------------------------------------------------- LayerNorm: fp32 x -> bf16 h
__global__ __launch_bounds__(256) void ln_kernel(
    const float* __restrict__ x, const float* __restrict__ w, const float* __restrict__ bb,
    u16* __restrict__ hb)
{
  int wid = threadIdx.x >> 6, lane = threadIdx.x & 63;
  int row = blockIdx.x * 4 + wid;
  const float* xr = x + row * 1024 + lane * 16;
  float xs[16];
#pragma unroll
  for (int i = 0; i < 4; i++) {
    float4 v = *(const float4*)(xr + i * 4);
    xs[i * 4 + 0] = v.x; xs[i * 4 + 1] = v.y; xs[i * 4 + 2] = v.z; xs[i * 4 + 3] = v.w;
  }
  float s = 0.f, ss = 0.f;
#pragma unroll
  for (int i = 0; i < 16; i++) { s += xs[i]; ss += xs[i] * xs[i]; }
#pragma unroll
  for (int m = 1; m < 64; m <<= 1) { s += __shfl_xor(s, m, 64); ss += __shfl_xor(ss, m, 64); }
  float mu = s * (1.0f / 1024.0f);
  float var = ss * (1.0f / 1024.0f) - mu * mu;
  float rstd = rsqrtf(var + 1e-5f);
  const float* wr = w + lane * 16;
  const float* br = bb + lane * 16;
  short8 o0, o1;
#pragma unroll
  for (int i = 0; i < 8; i++) {
    o0[i] = (short)f2bf((xs[i] - mu) * rstd * wr[i] + br[i]);
    o1[i] = (short)f2bf((xs[8 + i] - mu) * rstd * wr[8 + i] + br[8 + i]);
  }
  u16* hr = hb + row * 1024 + lane * 16;
  *(short8*)hr = o0;
  *(short8*)(hr + 8) = o1;
}

// ---------------------------------------------------------------- convert wq|wk|wv|wo fp32 -> bf16
__global__ __launch_bounds__(256) void convw_kernel(
    const float* __restrict__ wq, const float* __restrict__ wk,
    const float* __restrict__ wv, const float* __restrict__ wo,
    u16* __restrict__ wb)
{
  int idx = (blockIdx.x * 256 + threadIdx.x) * 8;  // [0, 4M)
  int seg = idx >> 20, off = idx & 1048575;
  const float* s = (seg == 0) ? wq : (seg == 1) ? wk : (seg == 2) ? wv : wo;
  float4 f0 = *(const float4*)(s + off);
  float4 f1 = *(const float4*)(s + off + 4);
  short8 o;
  o[0] = (short)f2bf(f0.x); o[1] = (short)f2bf(f0.y);
  o[2] = (short)f2bf(f0.z); o[3] = (short)f2bf(f0.w);
  o[4] = (short)f2bf(f1.x); o[5] = (short)f2bf(f1.y);
  o[6] = (short)f2bf(f1.z); o[7] = (short)f2bf(f1.w);
  *(short8*)&wb[idx] = o;
}

// ---------------------------------------------------------------- fused QKV GEMM (bf16 operands)
// C[4096][3072] = h[4096][1024] @ W^T ; W bf16 row-major [n][k].
// q scaled by 0.125 -> [b,h,t,hd]; k -> [b,h,t,hd]; v transposed -> [b,h,hd,t]. All bf16.
__global__ __launch_bounds__(256) void qkv_kernel(
    const u16* __restrict__ hb, const u16* __restrict__ wb,
    const float* __restrict__ bq, const float* __restrict__ bk, const float* __restrict__ bv,
    u16* __restrict__ qs, u16* __restrict__ kko, u16* __restrict__ vt)
{
  __shared__ u16 As[128 * 32];
  __shared__ u16 Bs[128 * 32];
  int tid = threadIdx.x;
  int wid = tid >> 6, lane = tid & 63;
  int wm = wid >> 1, wn = wid & 1;
  int l15 = lane & 15, quad = lane >> 4;
  int m0 = blockIdx.y * 128;
  int n0g = blockIdx.x * 128;
  int sec = n0g >> 10;
  int n0 = n0g & 1023;
  const u16* W = wb + sec * 1048576;
  const float* bias = (sec == 0) ? bq : ((sec == 1) ? bk : bv);

  floatx4 zero4 = {0.f, 0.f, 0.f, 0.f};
  floatx4 acc[4][4];
#pragma unroll
  for (int i = 0; i < 4; i++)
#pragma unroll
    for (int j = 0; j < 4; j++) acc[i][j] = zero4;

  int lr = tid >> 2;
  int lc = (tid & 3) * 8;

  for (int kt = 0; kt < 1024; kt += 32) {
    *(short8*)&As[lr * 32 + lc]        = *(const short8*)&hb[(m0 + lr) * 1024 + kt + lc];
    *(short8*)&As[(lr + 64) * 32 + lc] = *(const short8*)&hb[(m0 + lr + 64) * 1024 + kt + lc];
    *(short8*)&Bs[lr * 32 + lc]        = *(const short8*)&W[(n0 + lr) * 1024 + kt + lc];
    *(short8*)&Bs[(lr + 64) * 32 + lc] = *(const short8*)&W[(n0 + lr + 64) * 1024 + kt + lc];
    __syncthreads();
    short8 af[4], bf[4];
#pragma unroll
    for (int mi = 0; mi < 4; mi++)
      af[mi] = *(const short8*)&As[(wm * 64 + mi * 16 + l15) * 32 + quad * 8];
#pragma unroll
    for (int ni = 0; ni < 4; ni++)
      bf[ni] = *(const short8*)&Bs[(wn * 64 + ni * 16 + l15) * 32 + quad * 8];
#pragma unroll
    for (int mi = 0; mi < 4; mi++)
#pragma unroll
      for (int ni = 0; ni < 4; ni++)
        acc[mi][ni] = MFMA16(af[mi], bf[ni], acc[mi][ni]);
    __syncthreads();
  }

  int bidx = m0 >> 10;  // batch (128 divides 1024, so uniform per block)
#pragma unroll
  for (int mi = 0; mi < 4; mi++) {
#pragma unroll
    for (int ni = 0; ni < 4; ni++) {
#pragma unroll
      for (int r = 0; r < 4; r++) {
        int row = m0 + wm * 64 + mi * 16 + quad * 4 + r;
        int t = row & 1023;
        int c = n0 + wn * 64 + ni * 16 + l15;   // 0..1023 within section
        float val = acc[mi][ni][r] + bias[c];
        int hh = c >> 6, hp = c & 63;
        if (sec == 0) {
          val *= 0.125f;
          qs[((bidx * 16 + hh) * 1024 + t) * 64 + hp] = f2bf(val);
        } else if (sec == 1) {
          kko[((bidx * 16 + hh) * 1024 + t) * 64 + hp] = f2bf(val);
        } else {
          vt[((bidx * 16 + hh) * 64 + hp) * 1024 + t] = f2bf(val);
        }
      }
    }
  }
}

// ---------------------------------------------------------------- relative bucket + pos_bias (b=0 slice, fp32)
__device__ __forceinline__ int rel_bucket(int t, int s) {
  int rel = s - t;
  int bucket = (rel > 0) ? 160 : 0;
  int n = (rel < 0) ? -rel : rel;
  if (n < 80) return bucket + n;
  float a = logf((float)n / 80.0f);          // f32, mirrors np order of ops
  float c = a / (float)2.302585092994046;    // np.log(10.0)
  float v = c * 80.0f;
  int large = 80 + (int)v;                   // trunc toward zero (v >= 0)
  if (large > 159) large = 159;
  return bucket + large;
}

__global__ __launch_bounds__(256) void bias0_kernel(
    const float* __restrict__ rel_emb, float* __restrict__ out1)
{
  int tid = blockIdx.x * 256 + threadIdx.x;  // 131072 total
  int t = tid >> 7;
  int s0 = (tid & 127) * 8;
  int bkt[8];
#pragma unroll
  for (int j = 0; j < 8; j++) bkt[j] = rel_bucket(t, s0 + j) * 16;
  int base_ts = t * 1024 + s0;
#pragma unroll
  for (int hh = 0; hh < 16; hh++) {
    float4 v0, v1;
    v0.x = rel_emb[bkt[0] + hh]; v0.y = rel_emb[bkt[1] + hh];
    v0.z = rel_emb[bkt[2] + hh]; v0.w = rel_emb[bkt[3] + hh];
    v1.x = rel_emb[bkt[4] + hh]; v1.y = rel_emb[bkt[5] + hh];
    v1.z = rel_emb[bkt[6] + hh]; v1.w = rel_emb[bkt[7] + hh];
    float* p = out1 + hh * 1048576 + base_ts;
    *(float4*)p = v0;
    *(float4*)(p + 4) = v1;
  }
}

// ---------------------------------------------------------------- replicate b=0 bias slice to b=1,2,3
__global__ __launch_bounds__(256) void bias_copy_kernel(float* __restrict__ out1)
{
  int idx = blockIdx.x * 256 + threadIdx.x;  // [0, 4M) units of float4
  float4 v = *(const float4*)&out1[idx * 4];
  *(float4*)&out1[16777216 + idx * 4] = v;
  *(float4*)&out1[33554432 + idx * 4] = v;
  *(float4*)&out1[50331648 + idx * 4] = v;
}

// ---------------------------------------------------------------- flash attention (gate fused)
// grid (64 bh, 16 qtiles); 4 waves/block, each wave owns 16 q-rows, s-steps of 32.
__global__ __launch_bounds__(256) void attn_kernel(
    const u16* __restrict__ qs, const u16* __restrict__ kko, const u16* __restrict__ vt,
    const float* __restrict__ gw, const float* __restrict__ gb, const float* __restrict__ ga,
    const float* __restrict__ bias, u16* __restrict__ ao)
{
  __shared__ __align__(16) u16 Pb[4][16 * 32];
  int wid = threadIdx.x >> 6, lane = threadIdx.x & 63;
  int l15 = lane & 15, quad = lane >> 4;
  int bh = blockIdx.x;
  int b = bh >> 4, h = bh & 15;
  int q0 = blockIdx.y * 64 + wid * 16;
  const u16* Q = qs + bh * 65536;
  const u16* K = kko + bh * 65536;
  const u16* V = vt + bh * 65536;       // [hd][t]
  const float* Bi = bias + h * 1048576; // b=0 slice of pos_bias_out
  u16* pb = &Pb[wid][0];

  // ---- gate for row q0 + l15 (every lane computes; quads duplicate) ----
  const u16* qrow = Q + (q0 + l15) * 64;
  float e[8];
#pragma unroll
  for (int i = 0; i < 8; i++) e[i] = gb[i];
  for (int j = 0; j < 64; j++) {
    float ql = bf2f(qrow[j]) * 256.0f;  // qs holds q*0.125; ql = q_scaled*256
#pragma unroll
    for (int i = 0; i < 8; i++) e[i] += ql * gw[i * 64 + j];
  }
  float u0 = e[0] + e[1] + e[2] + e[3];
  float u1 = e[4] + e[5] + e[6] + e[7];
  float sa = 1.0f / (1.0f + __expf(-u0));
  float sb = 1.0f / (1.0f + __expf(-u1));
  float gv = sa * (sb * ga[h] - 1.0f) + 2.0f;

  short8 qf0 = *(const short8*)&Q[(q0 + l15) * 64 + quad * 8];
  short8 qf1 = *(const short8*)&Q[(q0 + l15) * 64 + quad * 8 + 32];
  float gt[4], mrun[4], lrun[4];
#pragma unroll
  for (int r = 0; r < 4; r++) {
    gt[r] = __shfl(gv, quad * 4 + r, 64);
    mrun[r] = -1e30f;
    lrun[r] = 0.f;
  }
  floatx4 zero4 = {0.f, 0.f, 0.f, 0.f};
  floatx4 accO[4];
#pragma unroll
  for (int ni = 0; ni < 4; ni++) accO[ni] = zero4;

  for (int s0 = 0; s0 < 1024; s0 += 32) {
    floatx4 sc0 = zero4, sc1 = zero4;
    short8 kf;
    kf = *(const short8*)&K[(s0 + l15) * 64 + quad * 8];
    sc0 = MFMA16(qf0, kf, sc0);
    kf = *(const short8*)&K[(s0 + l15) * 64 + quad * 8 + 32];
    sc0 = MFMA16(qf1, kf, sc0);
    kf = *(const short8*)&K[(s0 + 16 + l15) * 64 + quad * 8];
    sc1 = MFMA16(qf0, kf, sc1);
    kf = *(const short8*)&K[(s0 + 16 + l15) * 64 + quad * 8 + 32];
    sc1 = MFMA16(qf1, kf, sc1);

#pragma unroll
    for (int r = 0; r < 4; r++) {
      int t = q0 + quad * 4 + r;
      float v0 = sc0[r] + gt[r] * Bi[t * 1024 + s0 + l15];
      float v1 = sc1[r] + gt[r] * Bi[t * 1024 + s0 + 16 + l15];
      float mt = fmaxf(v0, v1);
#pragma unroll
      for (int m = 1; m < 16; m <<= 1) mt = fmaxf(mt, __shfl_xor(mt, m, 64));
      float mnew = fmaxf(mrun[r], mt);
      float alpha = __expf(fmaxf(mrun[r] - mnew, -80.0f));  // first-iter safe
      float p0 = __expf(v0 - mnew);
      float p1 = __expf(v1 - mnew);
      float ps = p0 + p1;
#pragma unroll
      for (int m = 1; m < 16; m <<= 1) ps += __shfl_xor(ps, m, 64);
      lrun[r] = lrun[r] * alpha + ps;
      mrun[r] = mnew;
#pragma unroll
      for (int ni = 0; ni < 4; ni++) accO[ni][r] *= alpha;
      pb[(quad * 4 + r) * 32 + l15] = f2bf(p0);
      pb[(quad * 4 + r) * 32 + 16 + l15] = f2bf(p1);
    }
    __syncthreads();   // uniform trip count; orders Pb write->read across the wave
    short8 pf = *(const short8*)&pb[l15 * 32 + quad * 8];
#pragma unroll
    for (int ni = 0; ni < 4; ni++) {
      short8 vf = *(const short8*)&V[(ni * 16 + l15) * 1024 + s0 + quad * 8];
      accO[ni] = MFMA16(pf, vf, accO[ni]);
    }
  }
#pragma unroll
  for (int ni = 0; ni < 4; ni++) {
#pragma unroll
    for (int r = 0; r < 4; r++) {
      int t = q0 + quad * 4 + r;
      float val = accO[ni][r] / lrun[r];
      ao[(b * 1024 + t) * 1024 + h * 64 + ni * 16 + l15] = f2bf(val);
    }
  }
}

// ---------------------------------------------------------------- output projection + residual (fp32 out)
__global__ __launch_bounds__(256) void oproj_kernel(
    const u16* __restrict__ ao, const u16* __restrict__ wob, const float* __restrict__ bo,
    const float* __restrict__ x, float* __restrict__ out)
{
  __shared__ u16 As[128 * 32];
  __shared__ u16 Bs[128 * 32];
  int tid = threadIdx.x;
  int wid = tid >> 6, lane = tid & 63;
  int wm = wid >> 1, wn = wid & 1;
  int l15 = lane & 15, quad = lane >> 4;
  int m0 = blockIdx.y * 128;
  int n0 = blockIdx.x * 128;

  floatx4 zero4 = {0.f, 0.f, 0.f, 0.f};
  floatx4 acc[4][4];
#pragma unroll
  for (int i = 0; i < 4; i++)
#pragma unroll
    for (int j = 0; j < 4; j++) acc[i][j] = zero4;

  int lr = tid >> 2;
  int lc = (tid & 3) * 8;

  for (int kt = 0; kt < 1024; kt += 32) {
    *(short8*)&As[lr * 32 + lc]        = *(const short8*)&ao[(m0 + lr) * 1024 + kt + lc];
    *(short8*)&As[(lr + 64) * 32 + lc] = *(const short8*)&ao[(m0 + lr + 64) * 1024 + kt + lc];
    *(short8*)&Bs[lr * 32 + lc]        = *(const short8*)&wob[(n0 + lr) * 1024 + kt + lc];
    *(short8*)&Bs[(lr + 64) * 32 + lc] = *(const short8*)&wob[(n0 + lr + 64) * 1024 + kt + lc];
    __syncthreads();
    short8 af[4], bf[4];
#pragma unroll
    for (int mi = 0; mi < 4; mi++)
      af[mi] = *(const short8*)&As[(wm * 64 + mi * 16 + l15) * 32 + quad * 8];
#pragma unroll
    for (int ni = 0; ni < 4; ni++)
      bf[ni] = *(const short8*)&Bs[(wn * 64 + ni * 16 + l15) * 32 + quad * 8];
#pragma unroll
    for (int mi = 0; mi < 4; mi++)
#pragma unroll
      for (int ni = 0; ni < 4; ni++)
        acc[mi][ni] = MFMA16(af[mi], bf[ni], acc[mi][ni]);
    __syncthreads();
  }

#pragma unroll
  for (int mi = 0; mi < 4; mi++) {
#pragma unroll
    for (int ni = 0; ni < 4; ni++) {
#pragma unroll
      for (int r = 0; r < 4; r++) {
        int row = m0 + wm * 64 + mi * 16 + quad * 4 + r;
        int c = n0 + wn * 64 + ni * 16 + l15;
        out[row * 1024 + c] = acc[mi][ni][r] + bo[c] + x[row * 1024 + c];
      }
    }
  }
}

// ---------------------------------------------------------------- launch
extern "C" void kernel_launch(void* const* d_in, const int* in_sizes, int n_in,
                              void* d_out, int out_size, void* d_ws, size_t ws_size,
                              hipStream_t stream) {
  const float* x    = (const float*)d_in[0];
  const float* ln_w = (const float*)d_in[1];
  const float* ln_b = (const float*)d_in[2];
  const float* wq   = (const float*)d_in[3];
  const float* bq   = (const float*)d_in[4];
  const float* wk   = (const float*)d_in[5];
  const float* bk   = (const float*)d_in[6];
  const float* wv   = (const float*)d_in[7];
  const float* bv   = (const float*)d_in[8];
  const float* wo   = (const float*)d_in[9];
  const float* bo   = (const float*)d_in[10];
  const float* rel  = (const float*)d_in[11];
  const float* gw   = (const float*)d_in[12];
  const float* gb   = (const float*)d_in[13];
  const float* ga   = (const float*)d_in[14];

  float* out0  = (float*)d_out;
  float* out1f = out0 + 4194304;   // pos_bias_out region, 64M floats (256 MB)

  // ---- bf16 scratch lives INSIDE out1's b=1 region ([16M,32M) floats = 64 MB).
  // d_ws untouched. bias_copy overwrites b=1..3 LAST, after all consumers.
  u16* hbb = (u16*)(out1f + 16777216);   // 8 MB  LN(x) bf16
  u16* wbb = (u16*)(out1f + 18874368);   // 8 MB  wq|wk|wv|wo bf16
  u16* qsb = (u16*)(out1f + 20971520);   // 8 MB  q*0.125 [b,h,t,hd]
  u16* kkb = (u16*)(out1f + 23068672);   // 8 MB  [b,h,t,hd]
  u16* vtb = (u16*)(out1f + 25165824);   // 8 MB  [b,h,hd,t]
  u16* aob = (u16*)(out1f + 27262976);   // 8 MB  attn out [b*t, d]

  ln_kernel<<<1024, 256, 0, stream>>>(x, ln_w, ln_b, hbb);
  convw_kernel<<<2048, 256, 0, stream>>>(wq, wk, wv, wo, wbb);
  qkv_kernel<<<dim3(24, 32), 256, 0, stream>>>(hbb, wbb, bq, bk, bv, qsb, kkb, vtb);
  bias0_kernel<<<512, 256, 0, stream>>>(rel, out1f);                   // b=0 slice (final data)
  attn_kernel<<<dim3(64, 16), 256, 0, stream>>>(qsb, kkb, vtb, gw, gb, ga, out1f, aob);
  oproj_kernel<<<dim3(8, 32), 256, 0, stream>>>(aob, wbb + 3145728, bo, x, out0);
  bias_copy_kernel<<<16384, 256, 0, stream>>>(out1f);                  // replicate b=0 -> b=1,2,3
}